// Round 2
// 1773.020 us; speedup vs baseline: 1.2567x; 1.2567x over previous
//
#include <hip/hip_runtime.h>
#include <cstdint>
#include <cstddef>

typedef unsigned short u16;
typedef __attribute__((ext_vector_type(8))) __bf16 bf16x8;
typedef __attribute__((ext_vector_type(4))) float f32x4;

// fp32 -> bf16 round-to-nearest-even (inputs are well-behaved, no NaN path)
__device__ __forceinline__ u16 f2bf(float f) {
  union { float f; unsigned u; } v; v.f = f;
  unsigned r = v.u + 0x7FFFu + ((v.u >> 16) & 1u);
  return (u16)(r >> 16);
}
__device__ __forceinline__ float bf2f(unsigned h) {
  union { unsigned u; float f; } v; v.u = h << 16;
  return v.f;
}

// ---------------------------------------------------------------- subdom loss
__global__ void init_loss_kernel(const float* __restrict__ c,
                                 const int* __restrict__ D,
                                 const int* __restrict__ K,
                                 float* __restrict__ out) {
  out[0] = -c[0] * (float)D[0] * (float)K[0];
}

__global__ void subdom_kernel(const float4* __restrict__ dm,
                              const float4* __restrict__ sl,
                              const float4* __restrict__ alpha4,
                              float* __restrict__ out, int n4, int k4mask) {
  const int stride = gridDim.x * blockDim.x;
  float s = 0.f;
  for (int i = blockIdx.x * blockDim.x + threadIdx.x; i < n4; i += stride) {
    float4 d = dm[i], l = sl[i], a = alpha4[i & k4mask];
    s += fmaxf(fmaf(a.x, l.x - d.x, 1.f), 0.f);
    s += fmaxf(fmaf(a.y, l.y - d.y, 1.f), 0.f);
    s += fmaxf(fmaf(a.z, l.z - d.z, 1.f), 0.f);
    s += fmaxf(fmaf(a.w, l.w - d.w, 1.f), 0.f);
  }
#pragma unroll
  for (int off = 32; off > 0; off >>= 1) s += __shfl_down(s, off, 64);
  __shared__ float red[4];
  const int lane = threadIdx.x & 63, wave = threadIdx.x >> 6;
  if (lane == 0) red[wave] = s;
  __syncthreads();
  if (threadIdx.x == 0) atomicAdd(out, red[0] + red[1] + red[2] + red[3]);
}

// ---------------------------------------------------------------- casts
__global__ void cast_f32_bf16_kernel(const float4* __restrict__ in,
                                     u16* __restrict__ out, int n4) {
  const int stride = gridDim.x * blockDim.x;
  for (int i = blockIdx.x * blockDim.x + threadIdx.x; i < n4; i += stride) {
    float4 v = in[i];
    uint2 p;
    p.x = (unsigned)f2bf(v.x) | ((unsigned)f2bf(v.y) << 16);
    p.y = (unsigned)f2bf(v.z) | ((unsigned)f2bf(v.w) << 16);
    ((uint2*)out)[i] = p;
  }
}

// in: [K,N] fp32 row-major  ->  out: [N,K] bf16 row-major
__global__ void transpose_cast_kernel(const float* __restrict__ in,
                                      u16* __restrict__ out, int K, int N) {
  __shared__ float tile[32][33];
  const int bx = blockIdx.x * 32;  // N
  const int by = blockIdx.y * 32;  // K
  const int tx = threadIdx.x, ty = threadIdx.y;
#pragma unroll
  for (int i = ty; i < 32; i += 8)
    tile[i][tx] = in[(size_t)(by + i) * N + bx + tx];
  __syncthreads();
#pragma unroll
  for (int i = ty; i < 32; i += 8)
    out[(size_t)(bx + i) * K + by + tx] = f2bf(tile[tx][i]);
}

// ---------------------------------------------------------------- GEMM
// 256x256 tile, BK=64, 8 waves (2Mx4N), 8-phase schedule with counted vmcnt.
//   LDS: per matrix 2 K-tile buffers x 2 k-half regions of [256 rows][32 k]
//        bf16 (16 KB each) = 64 KB; A+B = 128 KB.
//   Region rotation (iter computes tiles t0->buf0, t1=t0+1->buf1):
//     ph1,2 read buf0.kh0   ph3,4 read buf0.kh1
//     ph5,6 read buf1.kh0   ph7,8 read buf1.kh1
//   Stage slots (each = A or B region, 2 x global_load_lds dwordx4/thread),
//   every slot issues AFTER the barrier that freed its region:
//     ph1: A buf1.kh1 (t1)    ph2: B buf1.kh1 (t1)
//     ph3: A buf0.kh0 (t0+2)  ph4: B buf0.kh0 (t0+2)
//     ph5: A buf0.kh1 (t0+2)  ph6: B buf0.kh1 (t0+2)
//     ph7: A buf1.kh0 (t1+2)  ph8: B buf1.kh0 (t1+2)
//   Wait: s_waitcnt vmcnt(8) + s_barrier at end of each even phase -- the 8
//   newest outstanding loads are exactly the 4 stage slots younger than the
//   region needed next.  Never vmcnt(0) in steady state.
//   Bank swizzle (T2, involution on both sides): 16B slot s of row r holds
//   global k-chunk s^(r&3); applied on the global fetch address (gload_lds
//   writes linearly) and on the ds_read address.

__device__ __forceinline__ void gload_lds16(const void* g, void* l) {
  __builtin_amdgcn_global_load_lds(
      (const __attribute__((address_space(1))) void*)g,
      (__attribute__((address_space(3))) void*)l, 16, 0, 0);
}

#define VMW(N) asm volatile("s_waitcnt vmcnt(" #N ")" ::: "memory")

#define STAGE_A(BU, KH, TK)                                                   \
  do {                                                                        \
    gload_lds16(A + aoff0 + (size_t)((TK) * 64 + (KH) * 32),                  \
                (void*)(As + ((BU)*2 + (KH)) * 8192 + wslot));                \
    gload_lds16(A + aoff1 + (size_t)((TK) * 64 + (KH) * 32),                  \
                (void*)(As + ((BU)*2 + (KH)) * 8192 + 4096 + wslot));         \
  } while (0)

#define STAGE_B(BU, KH, TK)                                                   \
  do {                                                                        \
    gload_lds16(Bt + boff0 + (size_t)((TK) * 64 + (KH) * 32),                 \
                (void*)(Bs + ((BU)*2 + (KH)) * 8192 + wslot));                \
    gload_lds16(Bt + boff1 + (size_t)((TK) * 64 + (KH) * 32),                 \
                (void*)(Bs + ((BU)*2 + (KH)) * 8192 + 4096 + wslot));         \
  } while (0)

// One phase: ds_read frags | stage issue | bar | 16 MFMA | [wait] | bar
#define PH(BU, KH, MH, LB, STAGE_CODE, WAIT_CODE)                             \
  {                                                                           \
    const u16* Ar_ = As + ((BU)*2 + (KH)) * 8192 + (MH)*2048 + aread;         \
    bf16x8 af_[4];                                                            \
    af_[0] = *(const bf16x8*)(Ar_);                                           \
    af_[1] = *(const bf16x8*)(Ar_ + 512);                                     \
    af_[2] = *(const bf16x8*)(Ar_ + 1024);                                    \
    af_[3] = *(const bf16x8*)(Ar_ + 1536);                                    \
    if (LB) {                                                                 \
      const u16* Br_ = Bs + ((BU)*2 + (KH)) * 8192 + bread;                   \
      bfr[0] = *(const bf16x8*)(Br_);                                         \
      bfr[1] = *(const bf16x8*)(Br_ + 512);                                   \
      bfr[2] = *(const bf16x8*)(Br_ + 1024);                                  \
      bfr[3] = *(const bf16x8*)(Br_ + 1536);                                  \
    }                                                                         \
    STAGE_CODE;                                                               \
    __builtin_amdgcn_s_barrier();                                             \
    __builtin_amdgcn_s_setprio(1);                                            \
    _Pragma("unroll") for (int f_ = 0; f_ < 4; ++f_)                          \
      _Pragma("unroll") for (int n_ = 0; n_ < 4; ++n_)                        \
        acc[(MH)*4 + f_][n_] = __builtin_amdgcn_mfma_f32_16x16x32_bf16(       \
            af_[f_], bfr[n_], acc[(MH)*4 + f_][n_], 0, 0, 0);                 \
    __builtin_amdgcn_s_setprio(0);                                            \
    WAIT_CODE;                                                                \
    __builtin_amdgcn_s_barrier();                                             \
  }

// C[M,N] = act(A[M,K] @ Bt[N,K]^T + bias), bf16 in/out, fp32 accumulate.
// Requires M%256==0, N%256==0, K%128==0.
__global__ __launch_bounds__(512, 2) void gemm256(
    const u16* __restrict__ A, const u16* __restrict__ Bt,
    const float* __restrict__ bias, u16* __restrict__ C,
    int M, int N, int K, int act) {
  __shared__ __align__(16) u16 As[4 * 8192];  // 64 KB
  __shared__ __align__(16) u16 Bs[4 * 8192];  // 64 KB

  // XCD-aware block swizzle (nwg % 8 == 0 for all our grids)
  const int gx = gridDim.x;
  const int bid = blockIdx.x + blockIdx.y * gx;
  const int cpx = (gx * gridDim.y) >> 3;
  const int tilei = (bid & 7) * cpx + (bid >> 3);
  const int m0 = (tilei / gx) * 256;
  const int n0 = (tilei % gx) * 256;

  const int tid = threadIdx.x;
  const int wave = tid >> 6, lane = tid & 63;
  const int l15 = lane & 15, quad = lane >> 4;
  const int wm = wave >> 2, wn = wave & 3;  // 2 x 4 wave grid, 128x64 each

  // ds_read addresses (elements), swizzled slot = quad ^ (row&3)
  const int sl8 = ((quad ^ (l15 & 3)) << 3);
  const int aread = (wm * 128 + l15) * 32 + sl8;  // +MH*2048 +f*512
  const int bread = (wn * 64 + l15) * 32 + sl8;   // +f*512
  const int wslot = wave * 512;                   // LDS elems, wave-uniform

  // staging: thread t owns region chunks c=t and c=t+512; LDS linear,
  // global k-chunk = (c&3) ^ ((c>>2)&3)  (both-sides involution)
  const int r0 = tid >> 2;
  const int kn = (((tid & 3) ^ (r0 & 3)) << 3);
  const size_t aoff0 = (size_t)(m0 + r0) * K + kn;
  const size_t aoff1 = aoff0 + (size_t)128 * K;
  const size_t boff0 = (size_t)(n0 + r0) * K + kn;
  const size_t boff1 = boff0 + (size_t)128 * K;

  f32x4 acc[8][4];
#pragma unroll
  for (int i = 0; i < 8; ++i)
#pragma unroll
    for (int j = 0; j < 4; ++j) acc[i][j] = (f32x4){0.f, 0.f, 0.f, 0.f};
  bf16x8 bfr[4];

  // prologue: tile0 (both halves) + tile1 kh0; first 4 loads must land
  STAGE_A(0, 0, 0); STAGE_B(0, 0, 0);
  STAGE_A(0, 1, 0); STAGE_B(0, 1, 0);
  STAGE_A(1, 0, 1); STAGE_B(1, 0, 1);
  VMW(8);
  __builtin_amdgcn_s_barrier();

  const int niter = K >> 7;  // 2 K-tiles (BK=64) per iteration
  for (int it = 0; it < niter; ++it) {
    const int t1 = 2 * it + 1;
    const bool nl = (it + 1 < niter);
    PH(0, 0, 0, 1, { STAGE_A(1, 1, t1); }, {});
    PH(0, 0, 1, 0, { STAGE_B(1, 1, t1); }, { VMW(8); });
    PH(0, 1, 0, 1, { if (nl) STAGE_A(0, 0, t1 + 1); }, {});
    PH(0, 1, 1, 0, { if (nl) STAGE_B(0, 0, t1 + 1); },
       { if (nl) { VMW(8); } else { VMW(4); } });
    PH(1, 0, 0, 1, { if (nl) STAGE_A(0, 1, t1 + 1); }, {});
    PH(1, 0, 1, 0, { if (nl) STAGE_B(0, 1, t1 + 1); },
       { if (nl) { VMW(8); } else { VMW(0); } });
    PH(1, 1, 0, 1, { if (nl) STAGE_A(1, 0, t1 + 2); }, {});
    PH(1, 1, 1, 0, { if (nl) STAGE_B(1, 0, t1 + 2); },
       { if (nl) { VMW(8); } });
  }

  // epilogue: C/D layout col=lane&15, row=quad*4+reg (m89-verified)
#pragma unroll
  for (int mi = 0; mi < 8; ++mi) {
    const int row = m0 + wm * 128 + (mi >> 2) * 64 + (mi & 3) * 16 + quad * 4;
#pragma unroll
    for (int j = 0; j < 4; ++j) {
      const int col = n0 + wn * 64 + j * 16 + l15;
      const float bv = bias[col];
#pragma unroll
      for (int r = 0; r < 4; ++r) {
        float v = acc[mi][j][r] + bv;
        if (act) v = fmaxf(v, 0.f);
        C[(size_t)(row + r) * N + col] = f2bf(v);
      }
    }
  }
}

// ---------------------------------------------------------------- head: h@W4+b4, sigmoid
__global__ __launch_bounds__(256) void head_kernel(
    const u16* __restrict__ h, const float2* __restrict__ W4,
    const float* __restrict__ b4, float* __restrict__ out, int H) {
  const int row = blockIdx.x;
  const u16* hr = h + (size_t)row * H;
  const int tid = threadIdx.x;
  float p0 = 0.f, p1 = 0.f;
#pragma unroll
  for (int ii = 0; ii < 2; ++ii) {
    const int base = tid * 16 + ii * 8;  // 8 bf16 per uint4
    const uint4 hv = *(const uint4*)(hr + base);
    const unsigned uu[4] = {hv.x, hv.y, hv.z, hv.w};
#pragma unroll
    for (int j = 0; j < 4; ++j) {
      float a0 = bf2f(uu[j] & 0xffffu);
      float a1 = bf2f(uu[j] >> 16);
      float2 w0 = W4[base + 2 * j];
      float2 w1 = W4[base + 2 * j + 1];
      p0 += a0 * w0.x + a1 * w1.x;
      p1 += a0 * w0.y + a1 * w1.y;
    }
  }
#pragma unroll
  for (int off = 32; off > 0; off >>= 1) {
    p0 += __shfl_down(p0, off, 64);
    p1 += __shfl_down(p1, off, 64);
  }
  __shared__ float r0[4], r1[4];
  const int lane = tid & 63, wave = tid >> 6;
  if (lane == 0) { r0[wave] = p0; r1[wave] = p1; }
  __syncthreads();
  if (tid == 0) {
    float l0 = r0[0] + r0[1] + r0[2] + r0[3] + b4[0];
    float l1 = r1[0] + r1[1] + r1[2] + r1[3] + b4[1];
    out[1 + row * 2] = 1.f / (1.f + __expf(-l0));
    out[2 + row * 2] = 1.f / (1.f + __expf(-l1));
  }
}

// ---------------------------------------------------------------- launch
extern "C" void kernel_launch(void* const* d_in, const int* in_sizes, int n_in,
                              void* d_out, int out_size, void* d_ws,
                              size_t ws_size, hipStream_t stream) {
  (void)in_sizes; (void)n_in; (void)out_size; (void)ws_size;
  const float* x  = (const float*)d_in[0];
  const float* dm = (const float*)d_in[1];
  const float* al = (const float*)d_in[2];
  const float* sl = (const float*)d_in[3];
  const float* sc = (const float*)d_in[4];
  const int*   nd = (const int*)d_in[5];
  const int*   nf = (const int*)d_in[6];
  const float* W1 = (const float*)d_in[7];
  const float* b1 = (const float*)d_in[8];
  const float* W2 = (const float*)d_in[9];
  const float* b2 = (const float*)d_in[10];
  const float* W3 = (const float*)d_in[11];
  const float* b3 = (const float*)d_in[12];
  const float* W4 = (const float*)d_in[13];
  const float* b4 = (const float*)d_in[14];
  float* out = (float*)d_out;

  const int B = 16384, F = 2048, H = 4096, D = 4096, K = 2048;

  // workspace layout (352 MB): xb | wt | hA | hB
  char* ws = (char*)d_ws;
  u16* xb = (u16*)ws;                                         // B*F bf16
  u16* wt = (u16*)(ws + (size_t)B * F * 2);                   // H*H bf16 (reused W1t/W2t/W3t)
  u16* hA = (u16*)(ws + (size_t)B * F * 2 + (size_t)H * H * 2);
  u16* hB = hA + (size_t)B * H;

  // loss
  init_loss_kernel<<<1, 1, 0, stream>>>(sc, nd, nf, out);
  subdom_kernel<<<1024, 256, 0, stream>>>((const float4*)dm, (const float4*)sl,
                                          (const float4*)al, out, D * K / 4,
                                          K / 4 - 1);
  // MLP
  cast_f32_bf16_kernel<<<4096, 256, 0, stream>>>((const float4*)x, xb, B * F / 4);
  transpose_cast_kernel<<<dim3(H / 32, F / 32), dim3(32, 8), 0, stream>>>(W1, wt, F, H);
  gemm256<<<dim3(H / 256, B / 256), 512, 0, stream>>>(xb, wt, b1, hA, B, H, F, 1);
  transpose_cast_kernel<<<dim3(H / 32, H / 32), dim3(32, 8), 0, stream>>>(W2, wt, H, H);
  gemm256<<<dim3(H / 256, B / 256), 512, 0, stream>>>(hA, wt, b2, hB, B, H, H, 1);
  transpose_cast_kernel<<<dim3(H / 32, H / 32), dim3(32, 8), 0, stream>>>(W3, wt, H, H);
  gemm256<<<dim3(H / 256, B / 256), 512, 0, stream>>>(hB, wt, b3, hA, B, H, H, 1);
  head_kernel<<<B, 256, 0, stream>>>(hA, (const float2*)W4, b4, out, H);
}